// Round 4
// baseline (551.562 us; speedup 1.0000x reference)
//
#include <hip/hip_runtime.h>
#include <hip/hip_bf16.h>
#include <stdint.h>

#define IN_F 4096
#define OUT_F 4096
#define RANK 16
#define LORA_SCALE 2.0f

typedef __attribute__((ext_vector_type(8))) short short8;
typedef __attribute__((ext_vector_type(4))) float f32x4;
typedef __attribute__((ext_vector_type(16))) float f32x16;

__device__ __constant__ float NF4_CODE[16] = {
    -1.0f, -0.6961928009986877f, -0.5250730514526367f, -0.39491748809814453f,
    -0.28444138169288635f, -0.18477343022823334f, -0.09105003625154495f, 0.0f,
    0.07958029955625534f, 0.16093020141124725f, 0.24611230194568634f,
    0.33791524171829224f, 0.44070982933044434f, 0.5626170039176941f,
    0.7229568362236023f, 1.0f};

__device__ __forceinline__ short bf16_rne(float f) {
    uint32_t u = __builtin_bit_cast(uint32_t, f);
    u += 0x7fffu + ((u >> 16) & 1u);
    return (short)(u >> 16);
}

__device__ __forceinline__ void load_lds16(const short* g, short* l) {
    __builtin_amdgcn_global_load_lds(
        (const __attribute__((address_space(1))) void*)g,
        (__attribute__((address_space(3))) void*)l, 16, 0, 0);
}

// ---------------------------------------------------------------------------
// Fused prep (one launch):
//   blocks [0,4096):       W_eff[o][i] = NF4[codes]*absmax + 2*(Wa@Wb)^T  (bf16)
//   blocks [4096,4096+Nc): x fp32 -> bf16 cast, 2048 elems/block
// ---------------------------------------------------------------------------
__global__ __launch_bounds__(256)
void prep_kernel(const int* __restrict__ codes, const float* __restrict__ am,
                 const float* __restrict__ Wa, const float* __restrict__ Wb,
                 const float* __restrict__ x, short* __restrict__ Weff,
                 short* __restrict__ xb)
{
    const int tid = threadIdx.x;

    if (blockIdx.x >= 4096) {
        const size_t i = (size_t)(blockIdx.x - 4096) * 256 + tid;
        const f32x4* xv = (const f32x4*)x;
        f32x4 a = xv[2 * i], b = xv[2 * i + 1];
        short8 o;
        o[0] = bf16_rne(a[0]); o[1] = bf16_rne(a[1]);
        o[2] = bf16_rne(a[2]); o[3] = bf16_rne(a[3]);
        o[4] = bf16_rne(b[0]); o[5] = bf16_rne(b[1]);
        o[6] = bf16_rne(b[2]); o[7] = bf16_rne(b[3]);
        ((short8*)xb)[i] = o;
        return;
    }

    __shared__ float WaT[RANK * 64];   // [r][i_local]
    __shared__ float Wbs[RANK * 64];   // [r][o_local]

    const int iBase = (blockIdx.x & 63) * 64;
    const int oBase = (blockIdx.x >> 6) * 64;

    {
        f32x4 v = *(const f32x4*)(Wa + (size_t)iBase * RANK + tid * 4);
        #pragma unroll
        for (int j = 0; j < 4; j++) {
            int e = tid * 4 + j;                 // e = i_local*16 + r
            WaT[(e & 15) * 64 + (e >> 4)] = v[j];
        }
        int r = tid >> 4, c = (tid & 15) * 4;
        f32x4 w = *(const f32x4*)(Wb + (size_t)r * OUT_F + oBase + c);
        *(f32x4*)&Wbs[r * 64 + c] = w;
    }
    __syncthreads();

    #pragma unroll
    for (int p = 0; p < 2; p++) {
        const int g  = tid + p * 256;   // 512 groups: 64 o-rows x 8 i-groups
        const int o  = g >> 3;
        const int ig = (g & 7) * 8;
        const float amax = am[(size_t)(oBase + o) * (IN_F / 64) + (iBase >> 6)];

        const int4* cp = (const int4*)(codes + (size_t)(oBase + o) * IN_F + iBase + ig);
        int4 c0 = cp[0], c1 = cp[1];
        int cc[8] = {c0.x, c0.y, c0.z, c0.w, c1.x, c1.y, c1.z, c1.w};

        float acc[8] = {0, 0, 0, 0, 0, 0, 0, 0};
        #pragma unroll
        for (int r = 0; r < RANK; r++) {
            float wb = Wbs[r * 64 + o];
            f32x4 a0 = *(const f32x4*)&WaT[r * 64 + ig];
            f32x4 a1 = *(const f32x4*)&WaT[r * 64 + ig + 4];
            acc[0] += a0[0] * wb;  acc[1] += a0[1] * wb;
            acc[2] += a0[2] * wb;  acc[3] += a0[3] * wb;
            acc[4] += a1[0] * wb;  acc[5] += a1[1] * wb;
            acc[6] += a1[2] * wb;  acc[7] += a1[3] * wb;
        }

        short8 out;
        #pragma unroll
        for (int j = 0; j < 8; j++)
            out[j] = bf16_rne(NF4_CODE[cc[j] & 15] * amax + LORA_SCALE * acc[j]);
        *(short8*)(Weff + (size_t)(oBase + o) * IN_F + iBase + ig) = out;
    }
}

// ---------------------------------------------------------------------------
// Main GEMM: C[M][N] = A[M][K] * Bt[N][K]^T  (bf16 in, fp32 out)
// Block 128(M) x 256(N), BK=64, 256 thr.  4 waves, each 64x128 = 2x4 of
// mfma_f32_32x32x16_bf16 -> frag-read:mfma ratio 0.75 (was 1.0 at 2x2).
// XOR bank-swizzle on 8 k-chunks (slot = chunk ^ (row&7)); conflicts at this
// level measured cost-neutral (R2: zeroing them gained 0).
// A-frag: row=lane&31, k=(lane>>5)*8+j.  C/D: col=lane&31,
// row=(reg&3)+8*(reg>>2)+4*(lane>>5)  [m74/m101].
// ---------------------------------------------------------------------------
template<bool ABF16>
__global__ __launch_bounds__(256, 2)
void gemm32(const void* __restrict__ Ain, const short* __restrict__ Bt,
            float* __restrict__ C)
{
    __shared__ __align__(16) short lds[24576];  // A:[0,8192) B:[8192,24576)
    short* sA = lds;
    short* sB = lds + 8192;

    const int tid  = threadIdx.x;
    const int lane = tid & 63;
    const int wave = tid >> 6;
    const int mBase = blockIdx.y * 128;
    const int nBase = blockIdx.x * 256;
    const int wm = (wave >> 1) * 64;     // 0 / 64
    const int wn = (wave & 1) * 128;     // 0 / 128

    // staging: issue p covers 32 rows; thread t -> row p*32+(t>>3),
    // swizzled chunk (t&7)^(row&7); LDS dest (p*256+t)*16B (contiguous).
    const int srow = tid >> 3;                  // 0..31
    const int scol = ((tid & 7) ^ (srow & 7)) * 8;

    const short* gA[4]; const float* fA[4]; const short* gB[8];
    #pragma unroll
    for (int p = 0; p < 4; p++) {
        if constexpr (ABF16)
            gA[p] = (const short*)Ain + (size_t)(mBase + p * 32 + srow) * IN_F + scol;
        else
            fA[p] = (const float*)Ain + (size_t)(mBase + p * 32 + srow) * IN_F + scol;
    }
    #pragma unroll
    for (int p = 0; p < 8; p++)
        gB[p] = Bt + (size_t)(nBase + p * 32 + srow) * IN_F + scol;

    short* dA[4]; short* dB[8];
    #pragma unroll
    for (int p = 0; p < 4; p++) dA[p] = sA + (p * 256 + tid) * 8;
    #pragma unroll
    for (int p = 0; p < 8; p++) dB[p] = sB + (p * 256 + tid) * 8;

    // fragment addressing
    const int l31 = lane & 31;
    const int h   = lane >> 5;
    const int r7  = lane & 7;
    int xo[4];
    #pragma unroll
    for (int s = 0; s < 4; s++) xo[s] = ((s * 2 + h) ^ r7) * 8;
    const int rA0 = (wm + l31) * 64,        rA1 = rA0 + 32 * 64;
    int rB[4];
    #pragma unroll
    for (int ni = 0; ni < 4; ni++) rB[ni] = (wn + ni * 32 + l31) * 64;

    f32x16 acc[2][4];
    #pragma unroll
    for (int i = 0; i < 2; i++)
        #pragma unroll
        for (int j = 0; j < 4; j++)
            #pragma unroll
            for (int r = 0; r < 16; r++)
                acc[i][j][r] = 0.f;

    for (int k0 = 0; k0 < IN_F; k0 += 64) {
        if constexpr (ABF16) {
            #pragma unroll
            for (int p = 0; p < 4; p++) load_lds16(gA[p] + k0, dA[p]);
        } else {
            #pragma unroll
            for (int p = 0; p < 4; p++) {
                const float* s0 = fA[p] + k0;
                f32x4 v0 = *(const f32x4*)s0;
                f32x4 v1 = *(const f32x4*)(s0 + 4);
                short8 o;
                #pragma unroll
                for (int j = 0; j < 4; j++) {
                    o[j] = bf16_rne(v0[j]); o[j + 4] = bf16_rne(v1[j]);
                }
                *(short8*)dA[p] = o;
            }
        }
        #pragma unroll
        for (int p = 0; p < 8; p++) load_lds16(gB[p] + k0, dB[p]);
        __syncthreads();

        #pragma unroll
        for (int s = 0; s < 4; s++) {
            short8 a0 = *(const short8*)(sA + rA0 + xo[s]);
            short8 a1 = *(const short8*)(sA + rA1 + xo[s]);
            short8 b0 = *(const short8*)(sB + rB[0] + xo[s]);
            short8 b1 = *(const short8*)(sB + rB[1] + xo[s]);
            short8 b2 = *(const short8*)(sB + rB[2] + xo[s]);
            short8 b3 = *(const short8*)(sB + rB[3] + xo[s]);
            acc[0][0] = __builtin_amdgcn_mfma_f32_32x32x16_bf16(a0, b0, acc[0][0], 0, 0, 0);
            acc[1][0] = __builtin_amdgcn_mfma_f32_32x32x16_bf16(a1, b0, acc[1][0], 0, 0, 0);
            acc[0][1] = __builtin_amdgcn_mfma_f32_32x32x16_bf16(a0, b1, acc[0][1], 0, 0, 0);
            acc[1][1] = __builtin_amdgcn_mfma_f32_32x32x16_bf16(a1, b1, acc[1][1], 0, 0, 0);
            acc[0][2] = __builtin_amdgcn_mfma_f32_32x32x16_bf16(a0, b2, acc[0][2], 0, 0, 0);
            acc[1][2] = __builtin_amdgcn_mfma_f32_32x32x16_bf16(a1, b2, acc[1][2], 0, 0, 0);
            acc[0][3] = __builtin_amdgcn_mfma_f32_32x32x16_bf16(a0, b3, acc[0][3], 0, 0, 0);
            acc[1][3] = __builtin_amdgcn_mfma_f32_32x32x16_bf16(a1, b3, acc[1][3], 0, 0, 0);
        }
        __syncthreads();
    }

    // epilogue: C/D col=lane&31, row=(reg&3)+8*(reg>>2)+4*h
    #pragma unroll
    for (int mi = 0; mi < 2; mi++) {
        #pragma unroll
        for (int ni = 0; ni < 4; ni++) {
            const int col  = nBase + wn + ni * 32 + l31;
            const int rowb = mBase + wm + mi * 32 + 4 * h;
            #pragma unroll
            for (int r = 0; r < 16; r++) {
                const int row = rowb + (r & 3) + 8 * (r >> 2);
                C[(size_t)row * OUT_F + col] = acc[mi][ni][r];
            }
        }
    }
}

// ---------------------------------------------------------------------------
extern "C" void kernel_launch(void* const* d_in, const int* in_sizes, int n_in,
                              void* d_out, int out_size, void* d_ws, size_t ws_size,
                              hipStream_t stream)
{
    const float* x     = (const float*)d_in[0];
    const int*   codes = (const int*)d_in[1];
    const float* am    = (const float*)d_in[2];
    const float* Wa    = (const float*)d_in[3];
    const float* Wb    = (const float*)d_in[4];
    float* out = (float*)d_out;

    const int M = in_sizes[0] / IN_F;   // 8192 tokens

    short* Weff = (short*)d_ws;                          // OUT_F*IN_F bf16
    short* xb   = Weff + (size_t)OUT_F * IN_F;           // M*IN_F bf16
    const size_t need_full =
        ((size_t)OUT_F * IN_F + (size_t)M * IN_F) * sizeof(short);

    if (ws_size >= need_full) {
        const int castBlocks = (M * IN_F / 8) / 256;
        prep_kernel<<<4096 + castBlocks, 256, 0, stream>>>(
            codes, am, Wa, Wb, x, Weff, xb);
        gemm32<true><<<dim3(OUT_F / 256, M / 128), 256, 0, stream>>>(
            xb, Weff, out);
    } else {
        prep_kernel<<<4096, 256, 0, stream>>>(
            codes, am, Wa, Wb, x, Weff, Weff /*unused*/);
        gemm32<false><<<dim3(OUT_F / 256, M / 128), 256, 0, stream>>>(
            x, Weff, out);
    }
}